// Round 1
// baseline (381.976 us; speedup 1.0000x reference)
//
#include <hip/hip_runtime.h>

#define H 8
#define NSEQ 4096
#define DIM 64
#define BATCH 8
#define AREV_LEN 4224   // 4096 lags + 128 zero pad (covers negative-lag reads + parity shift)
#define HD (H*DIM)      // 512

typedef __attribute__((ext_vector_type(8))) short short8;
typedef __attribute__((ext_vector_type(4))) float float4v;

__device__ inline unsigned short f32_to_bf16(float f) {
    unsigned int u = __float_as_uint(f);
    u += 0x7fffu + ((u >> 16) & 1u);   // RNE
    return (unsigned short)(u >> 16);
}

// ---- P1: arev[hd][i] = bf16( exp(clamp(log(gamma)*k + pos[k-1])) ) at k = 4095 - i ----
// (k==0 uses `zero`). i in [4096,4224) stays 0 from the memset (negative lags).
__global__ __launch_bounds__(256) void build_arev(
    const float* __restrict__ zero, const float* __restrict__ pos,
    const float* __restrict__ gamma, unsigned short* __restrict__ arev)
{
    __shared__ unsigned short T[64][65];
    int h = blockIdx.y, kb = blockIdx.x;
    int tid = threadIdx.x;
    #pragma unroll
    for (int jj = 0; jj < 16; ++jj) {
        int e = tid + 256*jj;
        int kk = e >> 6, dd = e & 63;
        int k = kb*64 + kk;
        float v;
        if (k == 0) v = zero[h*64 + dd];
        else        v = logf(gamma[h*64 + dd]) * (float)k + pos[(h*4095 + (k-1))*64 + dd];
        v = fminf(30.f, fmaxf(-60.f, v));
        T[kk][dd] = f32_to_bf16(expf(v));
    }
    __syncthreads();
    int i0 = 4032 - kb*64;   // tile writes arev[hd][i0 .. i0+63], i = 4095 - k
    #pragma unroll
    for (int jj = 0; jj < 16; ++jj) {
        int e = tid + 256*jj;
        int dpr = e >> 6, ii = e & 63;
        arev[(size_t)(h*64 + dpr)*AREV_LEN + i0 + ii] = T[63 - ii][dpr];
    }
}

// ---- P2: xp[hd][b][s] = bf16(x[b][h][s][d])  (coalesced LDS transpose) ----
__global__ __launch_bounds__(256) void build_xp(
    const float* __restrict__ x, unsigned short* __restrict__ xp)
{
    __shared__ unsigned short T[64][65];
    int sb = blockIdx.x, h = blockIdx.y, b = blockIdx.z;
    int tid = threadIdx.x;
    const float* src = x + ((size_t)(b*H + h)*NSEQ + sb*64)*DIM;
    #pragma unroll
    for (int jj = 0; jj < 16; ++jj) {
        int e = tid + 256*jj;
        int ss = e >> 6, dd = e & 63;
        T[ss][dd] = f32_to_bf16(src[ss*64 + dd]);
    }
    __syncthreads();
    #pragma unroll
    for (int jj = 0; jj < 16; ++jj) {
        int e = tid + 256*jj;
        int dpr = e >> 6, ii = e & 63;
        xp[((size_t)(h*64 + dpr)*BATCH + b)*NSEQ + sb*64 + ii] = T[ii][dpr];
    }
}

// ---- GEMM: per (h,d): Out[t, 0:8] = sum_s a[t-s] * X[s, 0:8], causal ----
// One WG = one (h,d) and a 256-row t-tile. 4 waves x 4 sub-tiles of 16 rows.
// A-frags gathered from reversed kernel vector in LDS (lds1 = lds0 shifted by one
// element so every 8-bf16 run starts dword-aligned). No K-loop barriers.
__global__ __launch_bounds__(256) void toeplitz_gemm(
    const unsigned short* __restrict__ arev,
    const unsigned short* __restrict__ xp,
    float* __restrict__ out)
{
    __shared__ unsigned short lds0[AREV_LEN];
    __shared__ unsigned short lds1[AREV_LEN];

    // swizzle: 16 consecutive-d WGs (sharing 64B output lines) -> same XCD (id%8),
    // and big t-tiles first (tt descending).
    int id = blockIdx.x;
    int q8 = id >> 7, rem = id & 127;
    int r  = rem >> 3, xx = rem & 7;
    int g  = q8*8 + xx;
    int nlin = g*16 + r;
    int tt = 15 - (nlin >> 9);
    int h  = (nlin >> 6) & 7;
    int d  = nlin & 63;
    int hd = h*64 + d;
    int t0 = tt*256;

    int tid = threadIdx.x;
    const unsigned short* ga = arev + (size_t)hd*AREV_LEN;
    for (int i = tid; i < AREV_LEN; i += 256) lds0[i] = ga[i];
    for (int i = tid; i < AREV_LEN-1; i += 256) lds1[i] = ga[i+1];
    if (tid == 0) lds1[AREV_LEN-1] = 0;
    __syncthreads();

    int w = tid >> 6, lane = tid & 63;
    int nb = lane & 15;        // = A-frag row m and B-frag col n
    int q  = lane >> 4;        // k-quad
    int tw = t0 + 64*w;

    float4v acc[4];
    #pragma unroll
    for (int st = 0; st < 4; ++st) acc[st] = (float4v){0.f,0.f,0.f,0.f};

    const unsigned short* xrow = xp + ((size_t)hd*BATCH + nb)*NSEQ;
    const unsigned int* l32_0 = (const unsigned int*)lds0;
    const unsigned int* l32_1 = (const unsigned int*)lds1;

    int s_end  = tw + 64;            // causal bound for this wave's rows
    int base_i = 4095 - tw - nb;     // i0 = base_i - 16*st + s0 + 8*q

    #pragma unroll 2
    for (int s0 = 0; s0 < s_end; s0 += 32) {
        short8 bfrag = {0,0,0,0,0,0,0,0};
        if (nb < 8) bfrag = *reinterpret_cast<const short8*>(xrow + s0 + 8*q);
        int ibase = base_i + s0 + 8*q;
        #pragma unroll
        for (int st = 0; st < 4; ++st) {
            int i0 = ibase - 16*st;
            const unsigned int* l32 = (i0 & 1) ? l32_1 : l32_0;
            int dw = i0 >> 1;
            union { short8 v; unsigned int u[4]; } af;
            af.u[0] = l32[dw+0]; af.u[1] = l32[dw+1];
            af.u[2] = l32[dw+2]; af.u[3] = l32[dw+3];
            acc[st] = __builtin_amdgcn_mfma_f32_16x16x32_bf16(af.v, bfrag, acc[st], 0, 0, 0);
        }
    }

    // C/D: col(b) = lane&15, row(t within 16) = q*4 + rr
    if (nb < 8) {
        float* obase = out + ((size_t)(nb*H + h)*NSEQ)*DIM + d;
        #pragma unroll
        for (int st = 0; st < 4; ++st) {
            #pragma unroll
            for (int rr = 0; rr < 4; ++rr) {
                int t = tw + 16*st + 4*q + rr;
                obase[(size_t)t*DIM] = acc[st][rr];
            }
        }
    }
}

extern "C" void kernel_launch(void* const* d_in, const int* in_sizes, int n_in,
                              void* d_out, int out_size, void* d_ws, size_t ws_size,
                              hipStream_t stream) {
    const float* x     = (const float*)d_in[0];
    const float* zero  = (const float*)d_in[1];
    const float* pos   = (const float*)d_in[2];
    const float* gamma = (const float*)d_in[3];
    float* out = (float*)d_out;

    unsigned short* arev = (unsigned short*)d_ws;                 // 512*4224*2 = 4.33 MB
    unsigned short* xp   = arev + (size_t)HD*AREV_LEN;            // 512*8*4096*2 = 33.6 MB

    hipMemsetAsync(arev, 0, (size_t)HD*AREV_LEN*sizeof(unsigned short), stream);
    build_arev<<<dim3(64, 8), 256, 0, stream>>>(zero, pos, gamma, arev);
    build_xp<<<dim3(64, 8, 8), 256, 0, stream>>>(x, xp);
    toeplitz_gemm<<<dim3(512*16), 256, 0, stream>>>(arev, xp, out);
}

// Round 2
// 350.047 us; speedup vs baseline: 1.0912x; 1.0912x over previous
//
#include <hip/hip_runtime.h>

#define H 8
#define NSEQ 4096
#define DIM 64
#define BATCH 8
#define AREV_LEN 4256   // 4096 lags + 160 zero pad; 4256 elems = 2128 dwords == 16 mod 32
                        // -> lds1 (at +AREV_LEN) sits at bank offset +16 vs lds0: the two
                        // parity groups of a wave hit disjoint bank halves (no conflicts).
#define HD (H*DIM)      // 512

typedef __attribute__((ext_vector_type(8))) short short8;
typedef __attribute__((ext_vector_type(4))) float float4v;

__device__ inline unsigned short f32_to_bf16(float f) {
    unsigned int u = __float_as_uint(f);
    u += 0x7fffu + ((u >> 16) & 1u);   // RNE
    return (unsigned short)(u >> 16);
}

// ---- P1: arev[hd][i] = bf16( exp(clamp(log(gamma)*k + pos[k-1])) ) at k = 4095 - i ----
// (k==0 uses `zero`). i in [4096,4256) stays 0 from the memset (negative lags).
__global__ __launch_bounds__(256) void build_arev(
    const float* __restrict__ zero, const float* __restrict__ pos,
    const float* __restrict__ gamma, unsigned short* __restrict__ arev)
{
    __shared__ unsigned short T[64][65];
    int h = blockIdx.y, kb = blockIdx.x;
    int tid = threadIdx.x;
    #pragma unroll
    for (int jj = 0; jj < 16; ++jj) {
        int e = tid + 256*jj;
        int kk = e >> 6, dd = e & 63;
        int k = kb*64 + kk;
        float v;
        if (k == 0) v = zero[h*64 + dd];
        else        v = logf(gamma[h*64 + dd]) * (float)k + pos[(h*4095 + (k-1))*64 + dd];
        v = fminf(30.f, fmaxf(-60.f, v));
        T[kk][dd] = f32_to_bf16(expf(v));
    }
    __syncthreads();
    int i0 = 4032 - kb*64;   // tile writes arev[hd][i0 .. i0+63], i = 4095 - k
    #pragma unroll
    for (int jj = 0; jj < 16; ++jj) {
        int e = tid + 256*jj;
        int dpr = e >> 6, ii = e & 63;
        arev[(size_t)(h*64 + dpr)*AREV_LEN + i0 + ii] = T[63 - ii][dpr];
    }
}

// ---- P2: xp[hd][b][s] = bf16(x[b][h][s][d])  (coalesced LDS transpose) ----
__global__ __launch_bounds__(256) void build_xp(
    const float* __restrict__ x, unsigned short* __restrict__ xp)
{
    __shared__ unsigned short T[64][65];
    int sb = blockIdx.x, h = blockIdx.y, b = blockIdx.z;
    int tid = threadIdx.x;
    const float* src = x + ((size_t)(b*H + h)*NSEQ + sb*64)*DIM;
    #pragma unroll
    for (int jj = 0; jj < 16; ++jj) {
        int e = tid + 256*jj;
        int ss = e >> 6, dd = e & 63;
        T[ss][dd] = f32_to_bf16(src[ss*64 + dd]);
    }
    __syncthreads();
    #pragma unroll
    for (int jj = 0; jj < 16; ++jj) {
        int e = tid + 256*jj;
        int dpr = e >> 6, ii = e & 63;
        xp[((size_t)(h*64 + dpr)*BATCH + b)*NSEQ + sb*64 + ii] = T[ii][dpr];
    }
}

// ---- GEMM: per (h,d): Out[t, 0:8] = sum_s a[t-s] * X[s, 0:8], causal ----
// One WG = one (h,d) and a 256-row t-tile. 4 waves; each wave owns 4 sub-tiles of
// 16 rows spaced 32 apart in t, so frag(st+1) at s0+32 == frag(st) at s0: the
// K-loop loads ONE new A-fragment per iteration and rotates registers.
__global__ __launch_bounds__(256) void toeplitz_gemm(
    const unsigned short* __restrict__ arev,
    const unsigned short* __restrict__ xp,
    float* __restrict__ out)
{
    __shared__ unsigned short lds[2*AREV_LEN];   // [0]: arev, [AREV_LEN]: arev shifted +1

    // swizzle: 16 consecutive-d WGs (sharing 64B output lines) -> same XCD (id%8),
    // and big t-tiles first (tt descending).
    int id = blockIdx.x;
    int q8 = id >> 7, rem = id & 127;
    int r  = rem >> 3, xx = rem & 7;
    int g  = q8*8 + xx;
    int nlin = g*16 + r;
    int tt = 15 - (nlin >> 9);
    int h  = (nlin >> 6) & 7;
    int d  = nlin & 63;
    int hd = h*64 + d;
    int T0 = tt*256;

    int tid = threadIdx.x;
    const unsigned short* ga = arev + (size_t)hd*AREV_LEN;
    for (int i = tid; i < AREV_LEN; i += 256) lds[i] = ga[i];
    for (int i = tid; i < AREV_LEN-1; i += 256) lds[AREV_LEN + i] = ga[i+1];
    if (tid == 0) lds[2*AREV_LEN - 1] = 0;
    __syncthreads();

    int w = tid >> 6, lane = tid & 63;
    int nb = lane & 15;        // A-frag row m and B-frag col n (batch)
    int q  = lane >> 4;        // k-quad
    int b  = T0 + 16*(w & 1) + 128*(w >> 1);   // wave covers t in {b, b+32, b+64, b+96} +[0,16)

    float4v acc[4];
    #pragma unroll
    for (int st = 0; st < 4; ++st) acc[st] = (float4v){0.f,0.f,0.f,0.f};

    const unsigned short* xrow = xp + ((size_t)hd*BATCH + nb)*NSEQ;
    const unsigned int* l32_0 = (const unsigned int*)lds;
    const unsigned int* l32_1 = (const unsigned int*)(lds + AREV_LEN);

    int B0 = 4095 - b - nb;    // i0(s0) = B0 + s0 + 8q for sub-tile st=0

    auto loadfrag = [&](int s0) -> short8 {
        int i0 = B0 + s0 + 8*q;
        const unsigned int* l32 = (i0 & 1) ? l32_1 : l32_0;
        int dw = i0 >> 1;
        union { short8 v; unsigned int u[4]; } af;
        af.u[0] = l32[dw+0]; af.u[1] = l32[dw+1];
        af.u[2] = l32[dw+2]; af.u[3] = l32[dw+3];
        return af.v;
    };

    // pipeline prologue: f_k = frag for sub-tile k at s0=0 (real data, in-bounds)
    short8 f1 = loadfrag(-32);
    short8 f2 = loadfrag(-64);
    short8 f3 = loadfrag(-96);

    int s_end = b + 128; if (s_end > NSEQ) s_end = NSEQ;   // covers max t = b+127

    #pragma unroll 4
    for (int s0 = 0; s0 < s_end; s0 += 32) {
        short8 f0 = loadfrag(s0);
        short8 bf = {0,0,0,0,0,0,0,0};
        if (nb < 8) bf = *reinterpret_cast<const short8*>(xrow + s0 + 8*q);
        acc[0] = __builtin_amdgcn_mfma_f32_16x16x32_bf16(f0, bf, acc[0], 0, 0, 0);
        acc[1] = __builtin_amdgcn_mfma_f32_16x16x32_bf16(f1, bf, acc[1], 0, 0, 0);
        acc[2] = __builtin_amdgcn_mfma_f32_16x16x32_bf16(f2, bf, acc[2], 0, 0, 0);
        acc[3] = __builtin_amdgcn_mfma_f32_16x16x32_bf16(f3, bf, acc[3], 0, 0, 0);
        f3 = f2; f2 = f1; f1 = f0;
    }

    // C/D: col(b) = lane&15, row(t within 16) = q*4 + rr; sub-tile st at t base b+32*st
    if (nb < 8) {
        float* obase = out + ((size_t)(nb*H + h)*NSEQ)*DIM + d;
        #pragma unroll
        for (int st = 0; st < 4; ++st) {
            #pragma unroll
            for (int rr = 0; rr < 4; ++rr) {
                int t = b + 32*st + 4*q + rr;
                obase[(size_t)t*DIM] = acc[st][rr];
            }
        }
    }
}

extern "C" void kernel_launch(void* const* d_in, const int* in_sizes, int n_in,
                              void* d_out, int out_size, void* d_ws, size_t ws_size,
                              hipStream_t stream) {
    const float* x     = (const float*)d_in[0];
    const float* zero  = (const float*)d_in[1];
    const float* pos   = (const float*)d_in[2];
    const float* gamma = (const float*)d_in[3];
    float* out = (float*)d_out;

    unsigned short* arev = (unsigned short*)d_ws;                 // 512*4256*2 = 4.36 MB
    unsigned short* xp   = arev + (size_t)HD*AREV_LEN;            // 512*8*4096*2 = 33.6 MB

    hipMemsetAsync(arev, 0, (size_t)HD*AREV_LEN*sizeof(unsigned short), stream);
    build_arev<<<dim3(64, 8), 256, 0, stream>>>(zero, pos, gamma, arev);
    build_xp<<<dim3(64, 8, 8), 256, 0, stream>>>(x, xp);
    toeplitz_gemm<<<dim3(512*16), 256, 0, stream>>>(arev, xp, out);
}

// Round 3
// 327.119 us; speedup vs baseline: 1.1677x; 1.0701x over previous
//
#include <hip/hip_runtime.h>

#define H 8
#define NSEQ 4096
#define DIM 64
#define BATCH 8
#define AREV_LEN 4384   // 4096 lags + 288 zero pad (chain depth 8 + prefetch overrun).
                        // 4384 elems = 2192 dwords == 16 mod 32 -> lds1 sits at bank
                        // offset +16 vs lds0: parity groups hit disjoint bank halves.
#define HD (H*DIM)      // 512

typedef __attribute__((ext_vector_type(8))) short short8;
typedef __attribute__((ext_vector_type(4))) float float4v;

__device__ inline unsigned short f32_to_bf16(float f) {
    unsigned int u = __float_as_uint(f);
    u += 0x7fffu + ((u >> 16) & 1u);   // RNE
    return (unsigned short)(u >> 16);
}

// ---- P1: arev[hd][i] = bf16( exp(clamp(log(gamma)*k + pos[k-1])) ) at k = 4095 - i ----
// (k==0 uses `zero`). i in [4096,4384) stays 0 from the memset (negative lags).
__global__ __launch_bounds__(256) void build_arev(
    const float* __restrict__ zero, const float* __restrict__ pos,
    const float* __restrict__ gamma, unsigned short* __restrict__ arev)
{
    __shared__ unsigned short T[64][65];
    int h = blockIdx.y, kb = blockIdx.x;
    int tid = threadIdx.x;
    #pragma unroll
    for (int jj = 0; jj < 16; ++jj) {
        int e = tid + 256*jj;
        int kk = e >> 6, dd = e & 63;
        int k = kb*64 + kk;
        float v;
        if (k == 0) v = zero[h*64 + dd];
        else        v = logf(gamma[h*64 + dd]) * (float)k + pos[(h*4095 + (k-1))*64 + dd];
        v = fminf(30.f, fmaxf(-60.f, v));
        T[kk][dd] = f32_to_bf16(expf(v));
    }
    __syncthreads();
    int i0 = 4032 - kb*64;   // tile writes arev[hd][i0 .. i0+63], i = 4095 - k
    #pragma unroll
    for (int jj = 0; jj < 16; ++jj) {
        int e = tid + 256*jj;
        int dpr = e >> 6, ii = e & 63;
        arev[(size_t)(h*64 + dpr)*AREV_LEN + i0 + ii] = T[63 - ii][dpr];
    }
}

// ---- P2: xp[hd][b][s] = bf16(x[b][h][s][d])  (coalesced LDS transpose) ----
__global__ __launch_bounds__(256) void build_xp(
    const float* __restrict__ x, unsigned short* __restrict__ xp)
{
    __shared__ unsigned short T[64][65];
    int sb = blockIdx.x, h = blockIdx.y, b = blockIdx.z;
    int tid = threadIdx.x;
    const float* src = x + ((size_t)(b*H + h)*NSEQ + sb*64)*DIM;
    #pragma unroll
    for (int jj = 0; jj < 16; ++jj) {
        int e = tid + 256*jj;
        int ss = e >> 6, dd = e & 63;
        T[ss][dd] = f32_to_bf16(src[ss*64 + dd]);
    }
    __syncthreads();
    #pragma unroll
    for (int jj = 0; jj < 16; ++jj) {
        int e = tid + 256*jj;
        int dpr = e >> 6, ii = e & 63;
        xp[((size_t)(h*64 + dpr)*BATCH + b)*NSEQ + sb*64 + ii] = T[ii][dpr];
    }
}

// ---- GEMM: per (h,d): Out[t, 0:8] = sum_s a[t-s] * X[s, 0:8], causal ----
// One WG = one (h,d) and a 512-row t-tile. 4 waves; each wave owns 8 sub-tiles of
// 16 rows spaced 32 apart, so frag(j) at s0 == frag(j-1) at s0-32: the K-loop loads
// ONE new A-fragment per iteration, rotates a chain of 8, and runs 8 MFMAs on it.
__global__ __launch_bounds__(256) void toeplitz_gemm(
    const unsigned short* __restrict__ arev,
    const unsigned short* __restrict__ xp,
    float* __restrict__ out)
{
    __shared__ unsigned short lds[2*AREV_LEN];   // [0]: arev, [AREV_LEN]: arev shifted +1

    // swizzle: 16 line-sharing consecutive-d WGs -> same XCD (id%8); big t-tiles first.
    int id = blockIdx.x;                 // [0, 4096)
    int q8 = id >> 7, rem = id & 127;
    int r  = rem >> 3, xx = rem & 7;
    int g  = q8*8 + xx;                  // [0, 256)
    int nlin = g*16 + r;                 // [0, 4096)
    int tt = 7 - (nlin >> 9);
    int h  = (nlin >> 6) & 7;
    int d  = nlin & 63;
    int hd = h*64 + d;
    int T0 = tt*512;

    int tid = threadIdx.x;
    const unsigned short* ga = arev + (size_t)hd*AREV_LEN;
    for (int i = tid; i < AREV_LEN; i += 256) lds[i] = ga[i];
    for (int i = tid; i < AREV_LEN-1; i += 256) lds[AREV_LEN + i] = ga[i+1];
    if (tid == 0) lds[2*AREV_LEN - 1] = 0;
    __syncthreads();

    int w = tid >> 6, lane = tid & 63;
    int nb = lane & 15;        // A-frag row m and B-frag col n (batch)
    int q  = lane >> 4;        // k-quad
    int b  = T0 + 16*(w & 1) + 256*(w >> 1);   // wave: t in {b+32j, j<8} + [0,16)

    float4v acc[8];
    #pragma unroll
    for (int j = 0; j < 8; ++j) acc[j] = (float4v){0.f,0.f,0.f,0.f};

    const unsigned short* xrow = xp + ((size_t)hd*BATCH + (nb & 7))*NSEQ;
    const unsigned int* l32_0 = (const unsigned int*)lds;
    const unsigned int* l32_1 = (const unsigned int*)(lds + AREV_LEN);

    int B0 = 4095 - b - nb;    // i0(j, s0) = B0 - 32j + s0 + 8q

    auto loadfrag = [&](int s_ofs) -> short8 {
        int i0 = B0 + s_ofs + 8*q;
        const unsigned int* l32 = (i0 & 1) ? l32_1 : l32_0;
        int dw = i0 >> 1;
        union { short8 v; unsigned int u[4]; } af;
        af.u[0] = l32[dw+0]; af.u[1] = l32[dw+1];
        af.u[2] = l32[dw+2]; af.u[3] = l32[dw+3];
        return af.v;
    };

    // chain: f[j] = frag for sub-tile j at current s0
    short8 f[8];
    #pragma unroll
    for (int j = 1; j < 8; ++j) f[j] = loadfrag(-32*j);
    short8 nf = loadfrag(0);                                       // f[0] at s0=0
    short8 bnext = *reinterpret_cast<const short8*>(xrow + 8*q);   // B at s0=0

    int s_end = b + 240; if (s_end > NSEQ) s_end = NSEQ;  // covers max t = b+239

    #pragma unroll 8
    for (int s0 = 0; s0 < s_end; s0 += 32) {
        f[0] = nf;
        short8 bf = bnext;
        int sp = (s0 + 32 < s_end) ? (s0 + 32) : 0;   // scalar select, keeps prefetch in-bounds
        nf = loadfrag(sp);
        bnext = *reinterpret_cast<const short8*>(xrow + sp + 8*q);
        #pragma unroll
        for (int j = 7; j >= 0; --j)
            acc[j] = __builtin_amdgcn_mfma_f32_16x16x32_bf16(f[j], bf, acc[j], 0, 0, 0);
        #pragma unroll
        for (int j = 7; j >= 1; --j) f[j] = f[j-1];
    }

    // C/D: col(batch) = lane&15, row(t within 16) = q*4 + rr; sub-tile j at t base b+32j
    if (nb < 8) {
        float* obase = out + ((size_t)(nb*H + h)*NSEQ)*DIM + d;
        #pragma unroll
        for (int j = 0; j < 8; ++j) {
            #pragma unroll
            for (int rr = 0; rr < 4; ++rr) {
                int t = b + 32*j + 4*q + rr;
                obase[(size_t)t*DIM] = acc[j][rr];
            }
        }
    }
}

extern "C" void kernel_launch(void* const* d_in, const int* in_sizes, int n_in,
                              void* d_out, int out_size, void* d_ws, size_t ws_size,
                              hipStream_t stream) {
    const float* x     = (const float*)d_in[0];
    const float* zero  = (const float*)d_in[1];
    const float* pos   = (const float*)d_in[2];
    const float* gamma = (const float*)d_in[3];
    float* out = (float*)d_out;

    unsigned short* arev = (unsigned short*)d_ws;                 // 512*4384*2 = 4.49 MB
    unsigned short* xp   = arev + (size_t)HD*AREV_LEN;            // 512*8*4096*2 = 33.6 MB

    hipMemsetAsync(arev, 0, (size_t)HD*AREV_LEN*sizeof(unsigned short), stream);
    build_arev<<<dim3(64, 8), 256, 0, stream>>>(zero, pos, gamma, arev);
    build_xp<<<dim3(64, 8, 8), 256, 0, stream>>>(x, xp);
    toeplitz_gemm<<<dim3(512*8), 256, 0, stream>>>(arev, xp, out);
}